// Round 1
// baseline (236.905 us; speedup 1.0000x reference)
//
#include <hip/hip_runtime.h>
#include <hip/hip_bf16.h>

typedef unsigned short ushort_t;

#define N_IMG 32
#define C_IN  128
#define C_OUT 256
#define H_SZ  56
#define W_SZ  56
#define HW_SZ (H_SZ * W_SZ)        // 3136
#define K_TOT (C_IN * 9)           // 1152
#define WP 64                      // padded width  (w' = w+1, zeros at 0,57..63)
#define HP 58                      // padded height (h1 = h+1, zeros at 0,57)
#define ROW_E (WP * C_IN)          // 8192 elements per padded (n,h1) slab

typedef __attribute__((ext_vector_type(8))) short bf16x8;
typedef __attribute__((ext_vector_type(4))) float floatx4;

__device__ __forceinline__ void gl_lds16(const ushort_t* g, ushort_t* l) {
  __builtin_amdgcn_global_load_lds(
      (const __attribute__((address_space(1))) void*)g,
      (__attribute__((address_space(3))) void*)l, 16, 0, 0);
}

__device__ __forceinline__ ushort_t f2bf(float f) {
  __hip_bfloat16 b = __float2bfloat16(f);
  return *reinterpret_cast<ushort_t*>(&b);
}

// w_q (int32 {-1,0,1}, [co][c][kh][kw]) -> w_t bf16 [co][tap*128+c]
__global__ void wtrans_kernel(const int* __restrict__ wq, ushort_t* __restrict__ wt) {
  int idx = blockIdx.x * 256 + threadIdx.x;
  if (idx >= C_OUT * K_TOT) return;
  int co = idx / K_TOT;
  int k  = idx - co * K_TOT;
  int tap = k >> 7;
  int c   = k & 127;
  int kh = tap / 3, kw = tap - kh * 3;
  int v = wq[((co * C_IN + c) * 3 + kh) * 3 + kw];
  wt[idx] = f2bf((float)v);
}

// x fp32 NCHW -> xp bf16 padded-NHWC: xp[n][h1][w'][c], h1=h+1 (0,57 zero),
// w'=w+1 (0,57..63 zero), +1 slack row at the end (OOB spill for discarded cols).
__global__ __launch_bounds__(256) void xpad_kernel(const float* __restrict__ x,
                                                   ushort_t* __restrict__ xp) {
  int b = blockIdx.x;                 // 0..N_IMG*HP (last = slack row)
  int t = threadIdx.x;
  ushort_t* row = xp + (size_t)b * ROW_E;
  int n = b / HP;
  int h1 = b - n * HP;
  if (b >= N_IMG * HP || h1 == 0 || h1 == HP - 1) {
    uint4 z = {0u, 0u, 0u, 0u};
    uint4* r4 = (uint4*)row;          // 16384 B = 1024 uint4
#pragma unroll
    for (int i = 0; i < 4; ++i) r4[i * 256 + t] = z;
    return;
  }
  __shared__ float tile[C_IN * 57];   // stride 57: store-phase 4-way max (free-ish)
  int h = h1 - 1;
  const float* xb = x + (size_t)n * C_IN * HW_SZ + h * W_SZ;
#pragma unroll
  for (int i = 0; i < 7; ++i) {
    int idx = i * 256 + t;            // 0..1791 = 128 c * 14 float4
    int c = idx / 14, f = idx - c * 14;
    float4 v = *(const float4*)(xb + (size_t)c * HW_SZ + f * 4);
    float* dst = &tile[c * 57 + f * 4];
    dst[0] = v.x; dst[1] = v.y; dst[2] = v.z; dst[3] = v.w;
  }
  __syncthreads();
  unsigned int* r32 = (unsigned int*)row;
#pragma unroll
  for (int i = 0; i < 16; ++i) {
    int idx = i * 256 + t;            // 0..4095 = 64 w' * 64 cpair
    int wp = idx >> 6, cp = idx & 63;
    unsigned int u = 0;
    if (wp >= 1 && wp <= W_SZ) {
      int w = wp - 1;
      u = (unsigned int)f2bf(tile[(2 * cp) * 57 + w]) |
          ((unsigned int)f2bf(tile[(2 * cp + 1) * 57 + w]) << 16);
    }
    r32[wp * 64 + cp] = u;            // 256 B contiguous per w'
  }
}

// Implicit GEMM on padded layout, 2-phase double-buffered staging:
// issue step s+1's global_load_lds before waiting on step s, wait with
// counted s_waitcnt vmcnt(4) (never 0 in main loop), raw s_barrier so the
// compiler's __syncthreads vmcnt(0)-drain doesn't serialize the pipeline.
__global__ __launch_bounds__(256) void bitconv_kernel(
    const ushort_t* __restrict__ wt, const ushort_t* __restrict__ xp,
    const float* __restrict__ s, const float* __restrict__ bias,
    float* __restrict__ out) {
  __shared__ ushort_t As[2][128 * 32];   // 2 x 8 KB [co_local][c 32]
  __shared__ ushort_t Bs[2][128 * 32];   // 2 x 8 KB [sp_local][c 32]

  // XCD swizzle: XCD = d&7 gets contiguous sp range (xp slice ~3.8MB -> L2);
  // co-pair of one sp tile adjacent in dispatch on the same XCD.
  int d = blockIdx.x;                 // 1792 = 8 XCD * 2 co * 112 sp
  int xcd = d & 7;
  int r   = d >> 3;                   // 0..223
  int co0 = (r & 1) * 128;
  int sp_tile = xcd * 112 + (r >> 1); // 0..895
  int nh0 = sp_tile * 2;
  int n  = nh0 / H_SZ;
  int hh = nh0 - n * H_SZ;            // even; tile rows hh, hh+1

  int tid  = threadIdx.x;
  int lane = tid & 63;
  int wid  = tid >> 6;
  int l15  = lane & 15;
  int quad = lane >> 4;
  int wave_m = (wid >> 1) * 64;
  int wave_n = (wid & 1) * 64;
  int lrow = lane >> 2;               // 0..15
  int lchk = (lane & 3) * 8;          // element offset of 16B chunk

  // Staging: wave wid covers rows [wid*32, wid*32+32) of both A and B,
  // two 16-row groups each; per-lane source = row(lane>>2), chunk(lane&3)
  // -> LDS dest base + lane*16 exactly.
  const ushort_t* a_src[2];
  const ushort_t* b_src[2];
  int dst_off[2];
#pragma unroll
  for (int g = 0; g < 2; ++g) {
    int rrow = wid * 32 + g * 16 + lrow;        // 0..127
    a_src[g] = wt + (size_t)(co0 + rrow) * K_TOT + lchk;
    int hrow = rrow >> 6, wpp = (rrow & 63) + 1;
    b_src[g] = xp + (size_t)((n * HP + hh + 1 + hrow) * WP + wpp) * C_IN + lchk;
    dst_off[g] = (wid * 32 + g * 16) * 32;
  }

  floatx4 acc[4][4];
#pragma unroll
  for (int mi = 0; mi < 4; ++mi)
#pragma unroll
    for (int ni = 0; ni < 4; ++ni)
      acc[mi][ni] = (floatx4){0.f, 0.f, 0.f, 0.f};

  // stage step st (0..35: tap = st>>2, c0 = (st&3)*32) into buffer buf
  auto stage = [&](int st, int buf) {
    int tap = st >> 2;
    int c0  = (st & 3) << 5;
    int kh  = tap / 3;
    int kw  = tap - kh * 3;
    int aoff = tap * C_IN + c0;                       // uniform A offset
    int boff = (kh - 1) * ROW_E + (kw - 1) * C_IN + c0; // uniform B offset
#pragma unroll
    for (int g = 0; g < 2; ++g) {
      gl_lds16(a_src[g] + aoff, &As[buf][dst_off[g]]);
      gl_lds16(b_src[g] + boff, &Bs[buf][dst_off[g]]);
    }
  };

  stage(0, 0);
  int cur = 0;
  for (int st = 0; st < 36; ++st) {
    if (st < 35) {
      stage(st + 1, cur ^ 1);                    // 4 more loads in flight
      asm volatile("s_waitcnt vmcnt(4)" ::: "memory");  // step st's 4 done
    } else {
      asm volatile("s_waitcnt vmcnt(0)" ::: "memory");
    }
    __builtin_amdgcn_s_barrier();                // all waves: buf[cur] complete

    bf16x8 af[4], bfv[4];
#pragma unroll
    for (int mi = 0; mi < 4; ++mi)
      af[mi] = *(const bf16x8*)&As[cur][(wave_m + mi * 16 + l15) * 32 + quad * 8];
#pragma unroll
    for (int ni = 0; ni < 4; ++ni)
      bfv[ni] = *(const bf16x8*)&Bs[cur][(wave_n + ni * 16 + l15) * 32 + quad * 8];
#pragma unroll
    for (int mi = 0; mi < 4; ++mi)
#pragma unroll
      for (int ni = 0; ni < 4; ++ni)
        acc[mi][ni] = __builtin_amdgcn_mfma_f32_16x16x32_bf16(
            af[mi], bfv[ni], acc[mi][ni], 0, 0, 0);

    __builtin_amdgcn_s_barrier();                // all reads of buf[cur] done
    cur ^= 1;
  }

  // Epilogue: col(sp)=l15, row(co)=quad*4+reg; w'' = ni*16+l15, h_row = wid&1.
  int h_out = hh + (wid & 1);
#pragma unroll
  for (int mi = 0; mi < 4; ++mi) {
#pragma unroll
    for (int rg = 0; rg < 4; ++rg) {
      int co = co0 + wave_m + mi * 16 + quad * 4 + rg;
      float sv = s[co];
      float bv = bias[co];
      float* ob = out + (size_t)(n * C_OUT + co) * HW_SZ + h_out * W_SZ;
#pragma unroll
      for (int ni = 0; ni < 4; ++ni) {
        int wpp = ni * 16 + l15;      // 0..63 padded col
        if (wpp < W_SZ)
          ob[wpp] = acc[mi][ni][rg] * sv + bv;
      }
    }
  }
}

extern "C" void kernel_launch(void* const* d_in, const int* in_sizes, int n_in,
                              void* d_out, int out_size, void* d_ws, size_t ws_size,
                              hipStream_t stream) {
  const float* x    = (const float*)d_in[0];
  const int*   wq   = (const int*)d_in[1];
  const float* s    = (const float*)d_in[2];
  const float* bias = (const float*)d_in[3];
  float* out = (float*)d_out;

  char* ws = (char*)d_ws;
  ushort_t* wt = (ushort_t*)ws;                          // 589,824 B
  ushort_t* xp = (ushort_t*)(ws + 589824);               // (32*58+1)*16384 B ≈ 30.4 MB

  hipLaunchKernelGGL(wtrans_kernel, dim3((C_OUT * K_TOT) / 256), dim3(256), 0, stream,
                     wq, wt);
  hipLaunchKernelGGL(xpad_kernel, dim3(N_IMG * HP + 1), dim3(256), 0, stream, x, xp);
  hipLaunchKernelGGL(bitconv_kernel, dim3(1792), dim3(256), 0, stream,
                     wt, xp, s, bias, out);
}

// Round 2
// 216.679 us; speedup vs baseline: 1.0933x; 1.0933x over previous
//
#include <hip/hip_runtime.h>
#include <hip/hip_bf16.h>

typedef unsigned short ushort_t;

#define N_IMG 32
#define C_IN  128
#define C_OUT 256
#define H_SZ  56
#define W_SZ  56
#define HW_SZ (H_SZ * W_SZ)        // 3136
#define K_TOT (C_IN * 9)           // 1152
#define WP 64                      // padded width  (w' = w+1, zeros at 0,57..63)
#define HP 58                      // padded height (h1 = h+1, zeros at 0,57)
#define ROW_E (WP * C_IN)          // 8192 elements per padded (n,h1) slab

typedef __attribute__((ext_vector_type(8))) short bf16x8;
typedef __attribute__((ext_vector_type(4))) float floatx4;

__device__ __forceinline__ void gl_lds16(const ushort_t* g, ushort_t* l) {
  __builtin_amdgcn_global_load_lds(
      (const __attribute__((address_space(1))) void*)g,
      (__attribute__((address_space(3))) void*)l, 16, 0, 0);
}

__device__ __forceinline__ ushort_t f2bf(float f) {
  __hip_bfloat16 b = __float2bfloat16(f);
  return *reinterpret_cast<ushort_t*>(&b);
}

// w_q (int32 {-1,0,1}, [co][c][kh][kw]) -> w_t bf16 [co][tap*128+c]
__global__ void wtrans_kernel(const int* __restrict__ wq, ushort_t* __restrict__ wt) {
  int idx = blockIdx.x * 256 + threadIdx.x;
  if (idx >= C_OUT * K_TOT) return;
  int co = idx / K_TOT;
  int k  = idx - co * K_TOT;
  int tap = k >> 7;
  int c   = k & 127;
  int kh = tap / 3, kw = tap - kh * 3;
  int v = wq[((co * C_IN + c) * 3 + kh) * 3 + kw];
  wt[idx] = f2bf((float)v);
}

// x fp32 NCHW -> xp bf16 padded-NHWC: xp[n][h1][w'][c], h1=h+1 (0,57 zero),
// w'=w+1 (0,57..63 zero), +1 slack row at the end (OOB spill for discarded cols).
__global__ __launch_bounds__(256) void xpad_kernel(const float* __restrict__ x,
                                                   ushort_t* __restrict__ xp) {
  int b = blockIdx.x;                 // 0..N_IMG*HP (last = slack row)
  int t = threadIdx.x;
  ushort_t* row = xp + (size_t)b * ROW_E;
  int n = b / HP;
  int h1 = b - n * HP;
  if (b >= N_IMG * HP || h1 == 0 || h1 == HP - 1) {
    uint4 z = {0u, 0u, 0u, 0u};
    uint4* r4 = (uint4*)row;          // 16384 B = 1024 uint4
#pragma unroll
    for (int i = 0; i < 4; ++i) r4[i * 256 + t] = z;
    return;
  }
  __shared__ float tile[C_IN * 57];   // stride 57: store-phase 4-way max (free-ish)
  int h = h1 - 1;
  const float* xb = x + (size_t)n * C_IN * HW_SZ + h * W_SZ;
#pragma unroll
  for (int i = 0; i < 7; ++i) {
    int idx = i * 256 + t;            // 0..1791 = 128 c * 14 float4
    int c = idx / 14, f = idx - c * 14;
    float4 v = *(const float4*)(xb + (size_t)c * HW_SZ + f * 4);
    float* dst = &tile[c * 57 + f * 4];
    dst[0] = v.x; dst[1] = v.y; dst[2] = v.z; dst[3] = v.w;
  }
  __syncthreads();
  unsigned int* r32 = (unsigned int*)row;
#pragma unroll
  for (int i = 0; i < 16; ++i) {
    int idx = i * 256 + t;            // 0..4095 = 64 w' * 64 cpair
    int wp = idx >> 6, cp = idx & 63;
    unsigned int u = 0;
    if (wp >= 1 && wp <= W_SZ) {
      int w = wp - 1;
      u = (unsigned int)f2bf(tile[(2 * cp) * 57 + w]) |
          ((unsigned int)f2bf(tile[(2 * cp + 1) * 57 + w]) << 16);
    }
    r32[wp * 64 + cp] = u;            // 256 B contiguous per w'
  }
}

// Implicit GEMM, BK=64 double-buffered pipeline with XOR-swizzled LDS.
// 18 fully-unrolled steps (tap 0..8 x half 0..1), all offsets compile-time.
// Per step: issue next step's 8 global_load_lds, s_waitcnt vmcnt(8) (counted,
// never 0 in main loop), raw s_barrier, 16 ds_read_b128 + 32 MFMA, barrier.
// LDS layout: [row][slot], slot = chunk ^ (row&7) (chunk = 16B unit 0..7).
// Staging pre-swizzles the GLOBAL per-lane address (m173 both-sides rule):
// lane l fetches chunk (l&7)^(l>>3) so linear gl_lds dest lands swizzled.
// Swizzled reads spread 64 lanes over all 32 banks (2/bank = conflict-free).
__global__ __launch_bounds__(256) void bitconv_kernel(
    const ushort_t* __restrict__ wt, const ushort_t* __restrict__ xp,
    const float* __restrict__ s, const float* __restrict__ bias,
    float* __restrict__ out) {
  __shared__ ushort_t As[2][128 * 64];   // 2 x 16 KB [co_local][k 64]
  __shared__ ushort_t Bs[2][128 * 64];   // 2 x 16 KB [sp_local][k 64]

  // XCD swizzle: XCD = d&7 gets contiguous sp range (xp slice ~3.8MB -> L2);
  // co-pair of one sp tile adjacent in dispatch on the same XCD.
  int d = blockIdx.x;                 // 1792 = 8 XCD * 2 co * 112 sp
  int xcd = d & 7;
  int r   = d >> 3;                   // 0..223
  int co0 = (r & 1) * 128;
  int sp_tile = xcd * 112 + (r >> 1); // 0..895
  int nh0 = sp_tile * 2;
  int n  = nh0 / H_SZ;
  int hh = nh0 - n * H_SZ;            // even; tile rows hh, hh+1

  int tid  = threadIdx.x;
  int lane = tid & 63;
  int wid  = tid >> 6;
  int l15  = lane & 15;
  int quad = lane >> 4;
  int wave_m = (wid >> 1) * 64;
  int wave_n = (wid & 1) * 64;

  // Staging: wave wid owns rows [wid*32, wid*32+32), 4 groups of 8 rows.
  // Per-lane: row = g*8 + (lane>>3), fetched chunk q = (lane&7) ^ (lane>>3).
  int qoff = (((lane & 7) ^ (lane >> 3)) * 8);   // element offset of 16B chunk
  const ushort_t* a_src[4];
  const ushort_t* b_src[4];
  int dst_e[4];
#pragma unroll
  for (int g = 0; g < 4; ++g) {
    int rrow = wid * 32 + g * 8 + (lane >> 3);   // 0..127
    a_src[g] = wt + (size_t)(co0 + rrow) * K_TOT + qoff;
    int hrow = rrow >> 6, wpp = (rrow & 63) + 1;
    b_src[g] = xp + (size_t)((n * HP + hh + 1 + hrow) * WP + wpp) * C_IN + qoff;
    dst_e[g] = (wid * 32 + g * 8) * 64;
  }

  // Read-side swizzled chunk offsets (elements): chunk c = ks*4+quad,
  // slot = c ^ (l15&7); ks=1 flips bit2 -> ^32 elements.
  int koff0 = (quad ^ (l15 & 7)) * 8;
  int koff1 = koff0 ^ 32;

  floatx4 acc[4][4];
#pragma unroll
  for (int mi = 0; mi < 4; ++mi)
#pragma unroll
    for (int ni = 0; ni < 4; ++ni)
      acc[mi][ni] = (floatx4){0.f, 0.f, 0.f, 0.f};

  // stage (tap, half) into buffer buf — tap/half/buf always compile-time.
  auto stage = [&](int tap, int half, int buf) {
    int aoff = tap * C_IN + half * 64;                         // A: fits imm
    int boff = (tap / 3 - 1) * ROW_E + (tap % 3 - 1) * C_IN + half * 64;
#pragma unroll
    for (int g = 0; g < 4; ++g) {
      gl_lds16(a_src[g] + aoff, &As[buf][dst_e[g]]);
      gl_lds16(b_src[g] + boff, &Bs[buf][dst_e[g]]);
    }
  };

  stage(0, 0, 0);
#pragma unroll
  for (int st = 0; st < 18; ++st) {
    int buf = st & 1;
    if (st < 17) {
      stage((st + 1) >> 1, (st + 1) & 1, buf ^ 1);  // 8 more loads in flight
      asm volatile("s_waitcnt vmcnt(8)" ::: "memory");  // step st's 8 done
    } else {
      asm volatile("s_waitcnt vmcnt(0)" ::: "memory");
    }
    __builtin_amdgcn_s_barrier();                // all waves: buf complete
    asm volatile("" ::: "memory");

#pragma unroll
    for (int ks = 0; ks < 2; ++ks) {
      int ko = ks ? koff1 : koff0;
      bf16x8 af[4], bfv[4];
#pragma unroll
      for (int mi = 0; mi < 4; ++mi)
        af[mi] = *(const bf16x8*)&As[buf][(wave_m + mi * 16 + l15) * 64 + ko];
#pragma unroll
      for (int ni = 0; ni < 4; ++ni)
        bfv[ni] = *(const bf16x8*)&Bs[buf][(wave_n + ni * 16 + l15) * 64 + ko];
#pragma unroll
      for (int mi = 0; mi < 4; ++mi)
#pragma unroll
        for (int ni = 0; ni < 4; ++ni)
          acc[mi][ni] = __builtin_amdgcn_mfma_f32_16x16x32_bf16(
              af[mi], bfv[ni], acc[mi][ni], 0, 0, 0);
    }

    asm volatile("" ::: "memory");
    __builtin_amdgcn_s_barrier();                // all reads of buf done
    asm volatile("" ::: "memory");
  }

  // Epilogue: col(sp)=l15, row(co)=quad*4+reg; w'' = ni*16+l15, h_row = wid&1.
  int h_out = hh + (wid & 1);
#pragma unroll
  for (int mi = 0; mi < 4; ++mi) {
#pragma unroll
    for (int rg = 0; rg < 4; ++rg) {
      int co = co0 + wave_m + mi * 16 + quad * 4 + rg;
      float sv = s[co];
      float bv = bias[co];
      float* ob = out + (size_t)(n * C_OUT + co) * HW_SZ + h_out * W_SZ;
#pragma unroll
      for (int ni = 0; ni < 4; ++ni) {
        int wpp = ni * 16 + l15;      // 0..63 padded col
        if (wpp < W_SZ)
          ob[wpp] = acc[mi][ni][rg] * sv + bv;
      }
    }
  }
}

extern "C" void kernel_launch(void* const* d_in, const int* in_sizes, int n_in,
                              void* d_out, int out_size, void* d_ws, size_t ws_size,
                              hipStream_t stream) {
  const float* x    = (const float*)d_in[0];
  const int*   wq   = (const int*)d_in[1];
  const float* s    = (const float*)d_in[2];
  const float* bias = (const float*)d_in[3];
  float* out = (float*)d_out;

  char* ws = (char*)d_ws;
  ushort_t* wt = (ushort_t*)ws;                          // 589,824 B
  ushort_t* xp = (ushort_t*)(ws + 589824);               // (32*58+1)*16384 B ≈ 30.4 MB

  hipLaunchKernelGGL(wtrans_kernel, dim3((C_OUT * K_TOT) / 256), dim3(256), 0, stream,
                     wq, wt);
  hipLaunchKernelGGL(xpad_kernel, dim3(N_IMG * HP + 1), dim3(256), 0, stream, x, xp);
  hipLaunchKernelGGL(bitconv_kernel, dim3(1792), dim3(256), 0, stream,
                     wt, xp, s, bias, out);
}